// Round 1
// baseline (87.984 us; speedup 1.0000x reference)
//
#include <hip/hip_runtime.h>
#include <math.h>

typedef float v2f __attribute__((ext_vector_type(2)));
typedef float v4f __attribute__((ext_vector_type(4)));

#define TPB 256   // threads per block
#define IPT 4     // "self" rows per thread (registers)
#define JS  128   // j-slices per direction (split-K over the other cloud)

// ---------------------------------------------------------------------------
// AoSoA layout: each 2-point group g holds 8 floats:
//   [x(2g) x(2g+1) y(2g) y(2g+1) z(2g) z(2g+1) w(2g) w(2g+1)]
// so the pairs-kernel inner body is exactly two dwordx4 loads from one
// uniform base pointer (immediate offsets). Point i lives at
//   base = 8*(i>>1) + (i&1), components at base + {0,2,4,6}.
// ---------------------------------------------------------------------------

// Kernel 1 (fused setup): transform src, pack BOTH clouds interleaved,
// init pack arrays to u64-max, zero d_out, +INF sentinel pads (indices
// otherN and otherN+1) for the 2-wide tail reads.
__global__ __launch_bounds__(256) void setup_kernel(
    const float* __restrict__ ref, const float* __restrict__ src,
    const float* __restrict__ T,
    float* __restrict__ refI, float* __restrict__ srcI,
    unsigned long long* __restrict__ packF,
    unsigned long long* __restrict__ packB,
    float* __restrict__ out, int N, int M) {
  int i = blockIdx.x * blockDim.x + threadIdx.x;
  if (i < M) {
    float x = src[3 * i], y = src[3 * i + 1], z = src[3 * i + 2];
    float tx = T[0] * x + T[1] * y + T[2]  * z + T[3];
    float ty = T[4] * x + T[5] * y + T[6]  * z + T[7];
    float tz = T[8] * x + T[9] * y + T[10] * z + T[11];
    int base = 8 * (i >> 1) + (i & 1);
    srcI[base]     = tx;
    srcI[base + 2] = ty;
    srcI[base + 4] = tz;
    srcI[base + 6] = tx * tx + ty * ty + tz * tz;
    packB[i] = ~0ull;
  }
  if (i < N) {
    float x = ref[3 * i], y = ref[3 * i + 1], z = ref[3 * i + 2];
    int base = 8 * (i >> 1) + (i & 1);
    refI[base]     = x;
    refI[base + 2] = y;
    refI[base + 4] = z;
    refI[base + 6] = x * x + y * y + z * z;
    packF[i] = ~0ull;
  }
  if (i == 0) {
    out[0] = 0.0f;  // finalize accumulates via atomicAdd
#pragma unroll
    for (int e = 0; e < 2; e++) {  // sentinels at indices N..N+1, M..M+1
      int bn = 8 * ((N + e) >> 1) + ((N + e) & 1);
      refI[bn] = 0.f; refI[bn + 2] = 0.f; refI[bn + 4] = 0.f;
      refI[bn + 6] = INFINITY;
      int bm = 8 * ((M + e) >> 1) + ((M + e) & 1);
      srcI[bm] = 0.f; srcI[bm + 2] = 0.f; srcI[bm + 4] = 0.f;
      srcI[bm + 6] = INFINITY;
    }
  }
}

__device__ __forceinline__ unsigned int sortable(float f) {
  unsigned int u = __float_as_uint(f);
  return u ^ ((unsigned int)((int)u >> 31) | 0x80000000u);
}

// ---------------------------------------------------------------------------
// Kernel 2: fused bidirectional argmin over score_j = |q_j|^2 - 2 p.q_j
// (equal-argmin to squared distance; |p|^2 is row-constant). Index tracked
// INLINE (measured-best structure):
//   two j's per step: 2 dwordx4 loads + 3 v_pk_fma_f32/row + cmp/cndmask.
// FMA order identical to previous version -> bit-identical scores.
// Sequential strict-< selects preserve first-occurrence (smallest j) ==
// jnp.argmin. Split-K partials merged via sortable-key packed-u64 atomicMin.
// __launch_bounds__(TPB,4) caps VGPR <= 128 (>= 4 waves/SIMD); JS=128 gives
// 2048 blocks = 8 blocks/CU so extra occupancy headroom is fillable.
// ---------------------------------------------------------------------------
__global__ __launch_bounds__(TPB, 4) void pairs_kernel(
    const float* __restrict__ refI, const float* __restrict__ srcI,
    unsigned long long* __restrict__ packF,
    unsigned long long* __restrict__ packB,
    int N, int M, int nbF) {
  int b = blockIdx.x;
  const float *selfI, *otherI;
  unsigned long long* pack;
  int selfN, otherN;
  if (b < nbF) {  // forward: self = ref, other = transformed src
    selfI = refI; otherI = srcI; pack = packF; selfN = N; otherN = M;
  } else {        // backward: self = transformed src, other = ref
    b -= nbF;
    selfI = srcI; otherI = refI; pack = packB; selfN = M; otherN = N;
  }
  const int ib = b / JS, jb = b % JS;
  const int i0 = ib * (TPB * IPT) + threadIdx.x;

  float ax[IPT], ay[IPT], az[IPT], mind[IPT];
  int mini[IPT];
#pragma unroll
  for (int k = 0; k < IPT; k++) {
    int i = i0 + k * TPB;
    int ic = (i < selfN) ? i : (selfN - 1);  // clamp; guarded at atomic time
    int base = 8 * (ic >> 1) + (ic & 1);
    ax[k] = -2.0f * selfI[base];
    ay[k] = -2.0f * selfI[base + 2];
    az[k] = -2.0f * selfI[base + 4];
    mind[k] = INFINITY; mini[k] = 0;
  }

  int chunk = (otherN + JS - 1) / JS;
  chunk = (chunk + 1) & ~1;  // even -> 16B-aligned group loads
  const int j0 = jb * chunk;
  const int jcount = min(chunk, otherN - j0);  // may be <= 0

  // group stream: two v4f per 2-j group, uniform base + immediate offsets
  const v4f* og = (const v4f*)(otherI + 4 * j0);

#pragma unroll 4
  for (int jj = 0; jj < jcount; jj += 2) {
    v4f A = og[jj];      // {x0 x1 y0 y1}   (jj even -> og index = 2*(jj/2))
    v4f B = og[jj + 1];  // {z0 z1 w0 w1}
    v2f qx = __builtin_shufflevector(A, A, 0, 1);
    v2f qy = __builtin_shufflevector(A, A, 2, 3);
    v2f qz = __builtin_shufflevector(B, B, 0, 1);
    v2f qw = __builtin_shufflevector(B, B, 2, 3);
#pragma unroll
    for (int k = 0; k < IPT; k++) {
      v2f t = __builtin_elementwise_fma((v2f){ax[k], ax[k]}, qx, qw);
      t = __builtin_elementwise_fma((v2f){ay[k], ay[k]}, qy, t);
      t = __builtin_elementwise_fma((v2f){az[k], az[k]}, qz, t);
      if (t.x < mind[k]) { mind[k] = t.x; mini[k] = jj; }
      if (t.y < mind[k]) { mind[k] = t.y; mini[k] = jj + 1; }
    }
  }

#pragma unroll
  for (int k = 0; k < IPT; k++) {
    int i = i0 + k * TPB;
    if (i < selfN && jcount > 0) {
      unsigned long long p = ((unsigned long long)sortable(mind[k]) << 32) |
                             (unsigned int)(j0 + mini[k]);
      atomicMin(&pack[i], p);
    }
  }
}

// ---------------------------------------------------------------------------
// Kernel 3: trivial epilogue, thread-per-row (no rescan -- index is in the
// pack key). Exact fp32 distance recomputed from the winning index, sigma
// gather, log, mean; wave+LDS block reduce; one atomicAdd per block.
// ---------------------------------------------------------------------------
__global__ __launch_bounds__(256) void finalize_kernel(
    const unsigned long long* __restrict__ packF,
    const unsigned long long* __restrict__ packB,
    const float* __restrict__ refI, const float* __restrict__ srcI,
    const float* __restrict__ ref_sigma, const float* __restrict__ src_sigma,
    float* __restrict__ out, int N, int M) {
  int gid = blockIdx.x * blockDim.x + threadIdx.x;
  float term = 0.f;
  if (gid < N) {
    int idx = (int)(packF[gid] & 0xffffffffu);
    int sb = 8 * (gid >> 1) + (gid & 1);
    int ob = 8 * (idx >> 1) + (idx & 1);
    float dx = refI[sb]     - srcI[ob];
    float dy = refI[sb + 2] - srcI[ob + 2];
    float dz = refI[sb + 4] - srcI[ob + 4];
    float d = sqrtf(dx * dx + dy * dy + dz * dz);
    float sigma = 0.5f * (ref_sigma[gid] + src_sigma[idx]);
    term = (logf(sigma) + d / sigma) * (1.0f / (float)N);
  } else if (gid < N + M) {
    int j = gid - N;
    int idx = (int)(packB[j] & 0xffffffffu);
    int sb = 8 * (j >> 1) + (j & 1);
    int ob = 8 * (idx >> 1) + (idx & 1);
    float dx = srcI[sb]     - refI[ob];
    float dy = srcI[sb + 2] - refI[ob + 2];
    float dz = srcI[sb + 4] - refI[ob + 4];
    float d = sqrtf(dx * dx + dy * dy + dz * dz);
    float sigma = 0.5f * (src_sigma[j] + ref_sigma[idx]);
    term = (logf(sigma) + d / sigma) * (1.0f / (float)M);
  }
#pragma unroll
  for (int o = 32; o > 0; o >>= 1) term += __shfl_down(term, o, 64);
  __shared__ float wsum[4];
  const int lane = threadIdx.x & 63, wid = threadIdx.x >> 6;
  if (lane == 0) wsum[wid] = term;
  __syncthreads();
  if (threadIdx.x == 0)
    atomicAdd(out, wsum[0] + wsum[1] + wsum[2] + wsum[3]);
}

extern "C" void kernel_launch(void* const* d_in, const int* in_sizes, int n_in,
                              void* d_out, int out_size, void* d_ws,
                              size_t ws_size, hipStream_t stream) {
  const float* ref_kpts  = (const float*)d_in[0];
  const float* src_kpts  = (const float*)d_in[1];
  const float* gt        = (const float*)d_in[2];
  const float* ref_sigma = (const float*)d_in[3];
  const float* src_sigma = (const float*)d_in[4];
  float* out = (float*)d_out;

  const int N = in_sizes[0] / 3;
  const int M = in_sizes[1] / 3;

  // workspace: two AoSoA clouds (8 floats per 2-point group, +sentinel
  // group), then the two pack arrays (32B-aligned: group sizes are
  // multiples of 8 floats).
  const int NG8 = 8 * ((N + 3) / 2);
  const int MG8 = 8 * ((M + 3) / 2);
  float* f = (float*)d_ws;
  float* refI = f;
  float* srcI = f + NG8;
  unsigned long long* packF = (unsigned long long*)(f + NG8 + MG8);
  unsigned long long* packB = packF + N;

  int nPts = (N > M) ? N : M;
  setup_kernel<<<(nPts + 255) / 256, 256, 0, stream>>>(
      ref_kpts, src_kpts, gt, refI, srcI, packF, packB, out, N, M);

  const int ibF = (N + TPB * IPT - 1) / (TPB * IPT);  // row-blocks (forward)
  const int ibB = (M + TPB * IPT - 1) / (TPB * IPT);  // row-blocks (backward)
  const int nbF = ibF * JS;
  const int nbB = ibB * JS;
  pairs_kernel<<<nbF + nbB, TPB, 0, stream>>>(refI, srcI, packF, packB,
                                              N, M, nbF);

  finalize_kernel<<<(N + M + 255) / 256, 256, 0, stream>>>(
      packF, packB, refI, srcI, ref_sigma, src_sigma, out, N, M);
}